// Round 7
// baseline (313.858 us; speedup 1.0000x reference)
//
#include <hip/hip_runtime.h>
#include <math.h>

#define EMBED 1024
#define HDIM  64
#define BATCH 16
#define SEQ   2048
#define MTOT  (BATCH*SEQ)   // 32768
#define NE    (MTOT*HDIM)   // elements per Q/K/V array

typedef _Float16 f16;
typedef __attribute__((ext_vector_type(8))) _Float16 half8;   // 4 VGPR MFMA frag
typedef __attribute__((ext_vector_type(4))) _Float16 half4;   // 2 VGPR (mfma8 A/B)
typedef __attribute__((ext_vector_type(4))) float  float4v;   // 16x16 C/D frag
typedef __attribute__((ext_vector_type(16))) float float16v;  // 32x32 C/D frag

// ---------------------------------------------------------------------------
// Kernel 0: W -> fp16, transposed+concatenated: Wt[192][1024] (tiny)
// ---------------------------------------------------------------------------
__global__ void wprep_kernel(const float* __restrict__ Wq, const float* __restrict__ Wk,
                             const float* __restrict__ Wv, f16* __restrict__ Wt)
{
    int e = blockIdx.x * 256 + threadIdx.x;     // e = gn*1024 + k
    if (e >= 192 * EMBED) return;
    int gn = e >> 10, k = e & 1023;
    int mat = gn >> 6, n = gn & 63;
    const float* W = (mat == 0) ? Wq : ((mat == 1) ? Wk : Wv);
    Wt[e] = (f16)W[k * HDIM + n];
}

// ---------------------------------------------------------------------------
// Kernel 1: fused QKV projection, fp16 MFMA (unchanged).
// ---------------------------------------------------------------------------
__global__ __launch_bounds__(256)
void qkv_mfma_kernel(const float* __restrict__ X, const f16* __restrict__ Wt,
                     const float* __restrict__ bq, const float* __restrict__ bk, const float* __restrict__ bv,
                     f16* __restrict__ Q, f16* __restrict__ K, f16* __restrict__ Vt)
{
    __shared__ f16 Xs[64 * 72];    // [m][k] pad 64->72 halves
    __shared__ f16 Csv[64 * 72];   // V epilogue transpose [d][m]

    const int tid  = threadIdx.x;
    const int wave = tid >> 6;
    const int lane = tid & 63;
    const int quad = lane >> 4;
    const int c16  = lane & 15;
    const int m0   = blockIdx.x * 64;
    const int gnb  = wave * 3;

    float4v acc[4][3];
    #pragma unroll
    for (int mt = 0; mt < 4; ++mt)
        #pragma unroll
        for (int nt = 0; nt < 3; ++nt)
            acc[mt][nt] = (float4v){0.f, 0.f, 0.f, 0.f};

    float4 pf[4];
    #pragma unroll
    for (int i = 0; i < 4; ++i) {
        int c = tid + 256 * i, m = c >> 4, ko = (c & 15) * 4;
        pf[i] = *(const float4*)(X + (size_t)(m0 + m) * EMBED + ko);
    }

    for (int k0 = 0; k0 < EMBED; k0 += 64) {
        half8 bh[2][3];
        #pragma unroll
        for (int ks = 0; ks < 2; ++ks)
            #pragma unroll
            for (int nt = 0; nt < 3; ++nt)
                bh[ks][nt] = *(const half8*)(Wt + (size_t)((gnb + nt) * 16 + c16) * EMBED
                                             + k0 + ks * 32 + quad * 8);

        __syncthreads();
        #pragma unroll
        for (int i = 0; i < 4; ++i) {
            int c = tid + 256 * i, m = c >> 4, ko = (c & 15) * 4;
            *(half4*)&Xs[m * 72 + ko] =
                (half4){ (f16)pf[i].x, (f16)pf[i].y, (f16)pf[i].z, (f16)pf[i].w };
        }
        __syncthreads();

        {
            int k1 = (k0 + 64) & (EMBED - 1);
            #pragma unroll
            for (int i = 0; i < 4; ++i) {
                int c = tid + 256 * i, m = c >> 4, ko = (c & 15) * 4;
                pf[i] = *(const float4*)(X + (size_t)(m0 + m) * EMBED + k1 + ko);
            }
        }

        #pragma unroll
        for (int ks = 0; ks < 2; ++ks) {
            half8 a[4];
            #pragma unroll
            for (int mt = 0; mt < 4; ++mt)
                a[mt] = *(const half8*)&Xs[(mt * 16 + c16) * 72 + ks * 32 + quad * 8];
            #pragma unroll
            for (int mt = 0; mt < 4; ++mt)
                #pragma unroll
                for (int nt = 0; nt < 3; ++nt)
                    acc[mt][nt] = __builtin_amdgcn_mfma_f32_16x16x32_f16(a[mt], bh[ks][nt], acc[mt][nt], 0, 0, 0);
        }
    }

    float bb[3];
    #pragma unroll
    for (int nt = 0; nt < 3; ++nt) {
        int gn = (gnb + nt) * 16 + c16, mat = gn >> 6, cn = gn & 63;
        bb[nt] = ((mat == 0) ? bq : ((mat == 1) ? bk : bv))[cn];
    }

    #pragma unroll
    for (int mt = 0; mt < 4; ++mt)
        #pragma unroll
        for (int nt = 0; nt < 3; ++nt) {
            int gn = (gnb + nt) * 16 + c16, mat = gn >> 6, cn = gn & 63;
            if (mat < 2) {
                f16* O = mat ? K : Q;
                #pragma unroll
                for (int r = 0; r < 4; ++r)
                    O[(size_t)(m0 + mt * 16 + quad * 4 + r) * HDIM + cn] =
                        (f16)(acc[mt][nt][r] + bb[nt]);
            }
        }

    __syncthreads();
    #pragma unroll
    for (int mt = 0; mt < 4; ++mt)
        #pragma unroll
        for (int nt = 0; nt < 3; ++nt) {
            int gn = (gnb + nt) * 16 + c16, mat = gn >> 6, cn = gn & 63;
            if (mat == 2) {
                #pragma unroll
                for (int r = 0; r < 4; ++r)
                    Csv[cn * 72 + mt * 16 + quad * 4 + r] = (f16)(acc[mt][nt][r] + bb[nt]);
            }
        }
    __syncthreads();
    {
        int d = tid >> 2, ms = (tid & 3) * 16;
        #pragma unroll
        for (int j = 0; j < 2; ++j)
            *(half8*)(Vt + (size_t)d * MTOT + m0 + ms + 8 * j) =
                *(const half8*)&Csv[d * 72 + ms + 8 * j];
    }
}

// ---------------------------------------------------------------------------
// Kernel 2: flash attention — LDS-FREE, BARRIER-FREE, register-resident P.
//   All MFMA operands come straight from global (L2-resident K/V) or
//   registers:
//     S = mfma_32x32x16(A=K-row-frag (16B global load), B=Q-frag)
//       -> lane holds S[kv=(r&3)+8*(r>>2)+4*h5][q=lane&31]
//     exp+f16-pack in registers IS the A-frag of mfma_32x32x8f16;
//     V B-frags are 8B loads from Vt rows.
//   No __shared__ at all: no staging stores, no ds_reads, no barriers,
//   no lgkm/vmcnt drains — waves free-run; K-frags ping-pong prefetched.
//   L2 pays 2x reads (no cross-wave sharing) but K/V = 512KB/batch.
//   Split-KV z=2 (exact, fixed-shift softmax is linear); l = register sum
//   + shfl_xor(32); mask via one __ballot per tile.
//   block 128 = 2 waves x 32 q; grid (SEQ/64, BATCH, 2) = 1024 blocks.
// ---------------------------------------------------------------------------
__global__ __launch_bounds__(128)
void attn_mfma_kernel(const f16* __restrict__ Q, const f16* __restrict__ K,
                      const f16* __restrict__ Vt, const int* __restrict__ mask,
                      float* __restrict__ Opart0, float* __restrict__ Opart1,
                      float* __restrict__ Lpart)
{
    const int tid  = threadIdx.x;
    const int wave = tid >> 6;
    const int lane = tid & 63;
    const int r31  = lane & 31;
    const int h5   = lane >> 5;
    const int b    = blockIdx.y;
    const int kh   = blockIdx.z;
    const int q0   = blockIdx.x * 64 + wave * 32;   // 32 q-rows per wave
    const int kv0  = kh * (SEQ / 2);                // this block's kv half

    // Q B-frags: B[n=q=r31][k=d = i*16 + h5*8 + j], loaded once
    half8 qb[4];
    {
        const size_t qrow = (size_t)(b * SEQ + q0 + r31) * HDIM;
        #pragma unroll
        for (int i = 0; i < 4; ++i)
            qb[i] = *(const half8*)(Q + qrow + i * 16 + h5 * 8);
    }

    float16v O0 = {0.f}, O1 = {0.f};   // O[q][d cols r31 / 32+r31]
    float la[4] = {0.f, 0.f, 0.f, 0.f};

    const f16* Kb   = K + (size_t)b * SEQ * HDIM;   // K: [SEQ][64] for batch b
    const int vcol0 = b * SEQ + kv0;                // Vt: [64][MTOT]
    const int mbase = b * SEQ + kv0;

    // K A-frag loader: rows kv0+t+{r31, 32+r31}, 16B contiguous segments.
    // 4 i-loads x 2 lane-halves fully consume 32 rows x 128B -> perfect
    // cacheline utilization within the wave.
    auto LOADK = [&](half8* dst, int t) {
        #pragma unroll
        for (int i = 0; i < 4; ++i) {
            dst[i]     = *(const half8*)(Kb + (size_t)(kv0 + t + r31)      * HDIM + i * 16 + h5 * 8);
            dst[4 + i] = *(const half8*)(Kb + (size_t)(kv0 + t + 32 + r31) * HDIM + i * 16 + h5 * 8);
        }
    };

    half8 kA[8], kB[8];
    LOADK(kA, 0);
    int mA = mask[mbase + lane];
    int mB;

    // one kv-tile: QK^T from kc-frags, prefetch next K into kn, softmax, PV
    auto body = [&](half8* kc, half8* kn, int mcur, int& mnext, int t, int t1) {
        // prefetch next-tile K frags + mask (wraps on last; discarded)
        LOADK(kn, t1);
        mnext = mask[mbase + t1 + lane];

        // mask bits: kv of reg r (tile half tt) = tt*32 + (r&3)+8*(r>>2)+4*h5
        unsigned long long bits = __ballot(mcur != 0);
        unsigned long long shb  = bits >> (4 * h5);
        unsigned w0 = (unsigned)shb, w1 = (unsigned)(shb >> 32);

        // ---- S-tiles (swapped): D[m=kv][n=q] ----
        float16v sa = {0.f}, sb = {0.f};
        #pragma unroll
        for (int i = 0; i < 4; ++i) {
            sa = __builtin_amdgcn_mfma_f32_32x32x16_f16(kc[i],     qb[i], sa, 0, 0, 0);
            sb = __builtin_amdgcn_mfma_f32_32x32x16_f16(kc[4 + i], qb[i], sb, 0, 0, 0);
        }

        // ---- softmax (fixed shift), pack to PV A-frags in registers ----
        half4 pa0[4], pa1[4];         // [g][j]: kv = tt*32 + g*8 + 4*h5 + j
        #pragma unroll
        for (int g = 0; g < 4; ++g) {
            #pragma unroll
            for (int j2 = 0; j2 < 4; ++j2) {
                const int r  = 4 * g + j2;
                const int pc = (r & 3) + 8 * (r >> 2);
                float t0 = fmaf(sa[r], 0.125f, -6.0f);
                if (!((w0 >> pc) & 1)) t0 = -1e30f;
                f16 p0 = (f16)__expf(t0);
                pa0[g][j2] = p0;
                float t1f = fmaf(sb[r], 0.125f, -6.0f);
                if (!((w1 >> pc) & 1)) t1f = -1e30f;
                f16 p1 = (f16)__expf(t1f);
                pa1[g][j2] = p1;
                la[j2] += (float)p0 + (float)p1;   // l from the rounded P
            }
        }

        // ---- PV: O += P V; V B-frags = 8B Vt row segments from global ----
        #pragma unroll
        for (int g = 0; g < 4; ++g) {
            const int c0 = t + g * 8 + h5 * 4;   // kv-tile 0 cols
            const int c1 = 32 + c0;              // kv-tile 1 cols
            half4 vA0 = *(const half4*)(Vt + (size_t)(r31)      * MTOT + vcol0 + c0);
            half4 vA1 = *(const half4*)(Vt + (size_t)(r31)      * MTOT + vcol0 + c1);
            half4 vB0 = *(const half4*)(Vt + (size_t)(32 + r31) * MTOT + vcol0 + c0);
            half4 vB1 = *(const half4*)(Vt + (size_t)(32 + r31) * MTOT + vcol0 + c1);
            O0 = __builtin_amdgcn_mfma_f32_32x32x8f16(pa0[g], vA0, O0, 0, 0, 0);
            O0 = __builtin_amdgcn_mfma_f32_32x32x8f16(pa1[g], vA1, O0, 0, 0, 0);
            O1 = __builtin_amdgcn_mfma_f32_32x32x8f16(pa0[g], vB0, O1, 0, 0, 0);
            O1 = __builtin_amdgcn_mfma_f32_32x32x8f16(pa1[g], vB1, O1, 0, 0, 0);
        }
    };

    const int HALF = SEQ / 2;
    for (int t = 0; t < HALF; t += 128) {
        body(kA, kB, mA, mB, t,       (t + 64));
        body(kB, kA, mB, mA, t + 64, (t + 128) & (HALF - 1));
    }

    // ---- epilogue: partial l and partial (unnormalized) O ----
    float lsum = (la[0] + la[1]) + (la[2] + la[3]);   // this lane's kv subset
    lsum += __shfl_xor(lsum, 32, 64);                  // + partner half's subset
    if (lane < 32)
        Lpart[(size_t)kh * MTOT + b * SEQ + q0 + lane] = lsum;

    float* Ob = kh ? Opart1 : Opart0;
    #pragma unroll
    for (int r = 0; r < 16; ++r) {
        int q = (r & 3) + 8 * (r >> 2) + 4 * h5;
        size_t row = (size_t)(b * SEQ + q0 + q) * HDIM;
        Ob[row + r31]      = O0[r];
        Ob[row + 32 + r31] = O1[r];
    }
}

// ---------------------------------------------------------------------------
// Kernel 3: combine split-KV partials in-place: out = (out + O1) / (l0+l1)
// ---------------------------------------------------------------------------
__global__ __launch_bounds__(256)
void combine_kernel(const float* __restrict__ Op1, const float* __restrict__ Lp,
                    float* __restrict__ out)
{
    int e = (blockIdx.x * 256 + threadIdx.x) * 8;
    int m = e >> 6;   // row (8 floats stay within one 64-wide row)
    float inv = 1.0f / (Lp[m] + Lp[MTOT + m]);
    float4 a0 = *(const float4*)(out + e);
    float4 a1 = *(const float4*)(out + e + 4);
    float4 b0 = *(const float4*)(Op1 + e);
    float4 b1 = *(const float4*)(Op1 + e + 4);
    float4 r0, r1;
    r0.x = (a0.x + b0.x) * inv;  r0.y = (a0.y + b0.y) * inv;
    r0.z = (a0.z + b0.z) * inv;  r0.w = (a0.w + b0.w) * inv;
    r1.x = (a1.x + b1.x) * inv;  r1.y = (a1.y + b1.y) * inv;
    r1.z = (a1.z + b1.z) * inv;  r1.w = (a1.w + b1.w) * inv;
    *(float4*)(out + e)     = r0;
    *(float4*)(out + e + 4) = r1;
}

// ---------------------------------------------------------------------------
extern "C" void kernel_launch(void* const* d_in, const int* in_sizes, int n_in,
                              void* d_out, int out_size, void* d_ws, size_t ws_size,
                              hipStream_t stream) {
    const float* x    = (const float*)d_in[0];
    const int*   mask = (const int*)  d_in[1];
    const float* Wq   = (const float*)d_in[2];
    const float* bq   = (const float*)d_in[3];
    const float* Wk   = (const float*)d_in[4];
    const float* bk   = (const float*)d_in[5];
    const float* Wv   = (const float*)d_in[6];
    const float* bv   = (const float*)d_in[7];
    float* out = (float*)d_out;

    // workspace: Qf,Kf,Vt (fp16, 4MB each) + Wt (384KB) + Opart1 (8MB fp32)
    //            + Lpart (2x128KB fp32) ~= 21MB  (kh=0 partial lives in out)
    f16* Qf = (f16*)d_ws;
    f16* Kf = Qf + (size_t)NE;
    f16* Vt = Kf + (size_t)NE;
    f16* Wt = Vt + (size_t)NE;
    float* Opart1 = (float*)(Wt + 192 * EMBED);
    float* Lpart  = Opart1 + (size_t)MTOT * HDIM;

    wprep_kernel<<<dim3(768), dim3(256), 0, stream>>>(Wq, Wk, Wv, Wt);

    qkv_mfma_kernel<<<dim3(MTOT / 64), dim3(256), 0, stream>>>(
        x, Wt, bq, bk, bv, Qf, Kf, Vt);

    attn_mfma_kernel<<<dim3(SEQ / 64, BATCH, 2), dim3(128), 0, stream>>>(
        Qf, Kf, Vt, mask, out, Opart1, Lpart);

    combine_kernel<<<dim3((MTOT * HDIM) / (256 * 8)), dim3(256), 0, stream>>>(
        Opart1, Lpart, out);
}

// Round 8
// 288.728 us; speedup vs baseline: 1.0870x; 1.0870x over previous
//
#include <hip/hip_runtime.h>
#include <math.h>

#define EMBED 1024
#define HDIM  64
#define BATCH 16
#define SEQ   2048
#define MTOT  (BATCH*SEQ)   // 32768
#define NE    (MTOT*HDIM)   // elements per Q/K/V array
#define NKV   4             // split-KV ways

typedef _Float16 f16;
typedef __attribute__((ext_vector_type(8))) _Float16 half8;   // 4 VGPR MFMA frag
typedef __attribute__((ext_vector_type(4))) _Float16 half4;   // 2 VGPR (mfma8 A/B)
typedef __attribute__((ext_vector_type(4))) float  float4v;   // 16x16 C/D frag
typedef __attribute__((ext_vector_type(16))) float float16v;  // 32x32 C/D frag

// ---------------------------------------------------------------------------
// Kernel 0: W -> fp16, transposed+concatenated: Wt[192][1024] (tiny)
// ---------------------------------------------------------------------------
__global__ void wprep_kernel(const float* __restrict__ Wq, const float* __restrict__ Wk,
                             const float* __restrict__ Wv, f16* __restrict__ Wt)
{
    int e = blockIdx.x * 256 + threadIdx.x;     // e = gn*1024 + k
    if (e >= 192 * EMBED) return;
    int gn = e >> 10, k = e & 1023;
    int mat = gn >> 6, n = gn & 63;
    const float* W = (mat == 0) ? Wq : ((mat == 1) ? Wk : Wv);
    Wt[e] = (f16)W[k * HDIM + n];
}

// ---------------------------------------------------------------------------
// Kernel 1: fused QKV projection, fp16 MFMA (unchanged).
// ---------------------------------------------------------------------------
__global__ __launch_bounds__(256)
void qkv_mfma_kernel(const float* __restrict__ X, const f16* __restrict__ Wt,
                     const float* __restrict__ bq, const float* __restrict__ bk, const float* __restrict__ bv,
                     f16* __restrict__ Q, f16* __restrict__ K, f16* __restrict__ Vt)
{
    __shared__ f16 Xs[64 * 72];    // [m][k] pad 64->72 halves
    __shared__ f16 Csv[64 * 72];   // V epilogue transpose [d][m]

    const int tid  = threadIdx.x;
    const int wave = tid >> 6;
    const int lane = tid & 63;
    const int quad = lane >> 4;
    const int c16  = lane & 15;
    const int m0   = blockIdx.x * 64;
    const int gnb  = wave * 3;

    float4v acc[4][3];
    #pragma unroll
    for (int mt = 0; mt < 4; ++mt)
        #pragma unroll
        for (int nt = 0; nt < 3; ++nt)
            acc[mt][nt] = (float4v){0.f, 0.f, 0.f, 0.f};

    float4 pf[4];
    #pragma unroll
    for (int i = 0; i < 4; ++i) {
        int c = tid + 256 * i, m = c >> 4, ko = (c & 15) * 4;
        pf[i] = *(const float4*)(X + (size_t)(m0 + m) * EMBED + ko);
    }

    for (int k0 = 0; k0 < EMBED; k0 += 64) {
        half8 bh[2][3];
        #pragma unroll
        for (int ks = 0; ks < 2; ++ks)
            #pragma unroll
            for (int nt = 0; nt < 3; ++nt)
                bh[ks][nt] = *(const half8*)(Wt + (size_t)((gnb + nt) * 16 + c16) * EMBED
                                             + k0 + ks * 32 + quad * 8);

        __syncthreads();
        #pragma unroll
        for (int i = 0; i < 4; ++i) {
            int c = tid + 256 * i, m = c >> 4, ko = (c & 15) * 4;
            *(half4*)&Xs[m * 72 + ko] =
                (half4){ (f16)pf[i].x, (f16)pf[i].y, (f16)pf[i].z, (f16)pf[i].w };
        }
        __syncthreads();

        {
            int k1 = (k0 + 64) & (EMBED - 1);
            #pragma unroll
            for (int i = 0; i < 4; ++i) {
                int c = tid + 256 * i, m = c >> 4, ko = (c & 15) * 4;
                pf[i] = *(const float4*)(X + (size_t)(m0 + m) * EMBED + k1 + ko);
            }
        }

        #pragma unroll
        for (int ks = 0; ks < 2; ++ks) {
            half8 a[4];
            #pragma unroll
            for (int mt = 0; mt < 4; ++mt)
                a[mt] = *(const half8*)&Xs[(mt * 16 + c16) * 72 + ks * 32 + quad * 8];
            #pragma unroll
            for (int mt = 0; mt < 4; ++mt)
                #pragma unroll
                for (int nt = 0; nt < 3; ++nt)
                    acc[mt][nt] = __builtin_amdgcn_mfma_f32_16x16x32_f16(a[mt], bh[ks][nt], acc[mt][nt], 0, 0, 0);
        }
    }

    float bb[3];
    #pragma unroll
    for (int nt = 0; nt < 3; ++nt) {
        int gn = (gnb + nt) * 16 + c16, mat = gn >> 6, cn = gn & 63;
        bb[nt] = ((mat == 0) ? bq : ((mat == 1) ? bk : bv))[cn];
    }

    #pragma unroll
    for (int mt = 0; mt < 4; ++mt)
        #pragma unroll
        for (int nt = 0; nt < 3; ++nt) {
            int gn = (gnb + nt) * 16 + c16, mat = gn >> 6, cn = gn & 63;
            if (mat < 2) {
                f16* O = mat ? K : Q;
                #pragma unroll
                for (int r = 0; r < 4; ++r)
                    O[(size_t)(m0 + mt * 16 + quad * 4 + r) * HDIM + cn] =
                        (f16)(acc[mt][nt][r] + bb[nt]);
            }
        }

    __syncthreads();
    #pragma unroll
    for (int mt = 0; mt < 4; ++mt)
        #pragma unroll
        for (int nt = 0; nt < 3; ++nt) {
            int gn = (gnb + nt) * 16 + c16, mat = gn >> 6, cn = gn & 63;
            if (mat == 2) {
                #pragma unroll
                for (int r = 0; r < 4; ++r)
                    Csv[cn * 72 + mt * 16 + quad * 4 + r] = (f16)(acc[mt][nt][r] + bb[nt]);
            }
        }
    __syncthreads();
    {
        int d = tid >> 2, ms = (tid & 3) * 16;
        #pragma unroll
        for (int j = 0; j < 2; ++j)
            *(half8*)(Vt + (size_t)d * MTOT + m0 + ms + 8 * j) =
                *(const half8*)&Csv[d * 72 + ms + 8 * j];
    }
}

// ---------------------------------------------------------------------------
// Kernel 2: flash attention, register-resident P + LDS-staged K/V (r5 base),
//   OCCUPANCY DOUBLED: single-buffer LDS (18.4 KB) + split-KV z=4 ->
//   grid (SEQ/64, BATCH, 4) = 2048 blocks = 8 blocks/CU (LDS-capped) =
//   16 waves/CU (2x every prior design). 8 independent blocks per CU cover
//   the 2-barriers/iter stalls (r7 counters: latency-bound at 20% occupancy).
//   Swapped QK^T: S = mfma_32x32x16(A=K, B=Q); lane holds
//   S[kv=(r&3)+8*(r>>2)+4*h5][q=r31]; exp+f16-pack in registers IS the
//   A-frag of mfma_32x32x8f16 for PV. l = register sum + shfl_xor(32).
//   Mask via one __ballot per tile. Fixed-shift softmax (linear -> split-KV
//   exact). kh=0 partial O -> out; kh=1..3 -> workspace slabs.
// ---------------------------------------------------------------------------
__global__ __launch_bounds__(128, 4)
void attn_mfma_kernel(const f16* __restrict__ Q, const f16* __restrict__ K,
                      const f16* __restrict__ Vt, const int* __restrict__ mask,
                      float* __restrict__ Oout, float* __restrict__ Opart,
                      float* __restrict__ Lpart)
{
    __shared__ f16 Ks[64 * 72];   // [kv][d] pad 64->72 (single buffer)
    __shared__ f16 Vs[64 * 72];   // [d][kv]

    const int tid  = threadIdx.x;
    const int wave = tid >> 6;
    const int lane = tid & 63;
    const int r31  = lane & 31;
    const int h5   = lane >> 5;
    const int b    = blockIdx.y;
    const int kh   = blockIdx.z;
    const int q0   = blockIdx.x * 64 + wave * 32;   // 32 q-rows per wave
    const int kv0  = kh * (SEQ / NKV);              // this block's kv quarter

    // Q B-frags: B[n=q=r31][k=d = i*16 + h5*8 + j], loaded once
    half8 qb[4];
    {
        const size_t qrow = (size_t)(b * SEQ + q0 + r31) * HDIM;
        #pragma unroll
        for (int i = 0; i < 4; ++i)
            qb[i] = *(const half8*)(Q + qrow + i * 16 + h5 * 8);
    }

    float16v O0 = {0.f}, O1 = {0.f};   // O[q][d cols r31 / 32+r31]
    float la[4] = {0.f, 0.f, 0.f, 0.f};

    const size_t kbase = (size_t)b * SEQ * HDIM;   // K: [SEQ][64] per batch
    const int vcol0 = b * SEQ + kv0;               // Vt: [64][MTOT]
    const int mbase = b * SEQ + kv0;

    // register prefetch of tile 0 (K,V: 8KB each; 128 thr -> 4 half8 each)
    half8 pfK[4], pfV[4];
    #pragma unroll
    for (int i = 0; i < 4; ++i) {
        int c = tid + 128 * i, j = c >> 3, o = (c & 7) * 8;
        pfK[i] = *(const half8*)(K  + kbase + (size_t)(kv0 + j) * HDIM + o);
        pfV[i] = *(const half8*)(Vt + (size_t)j * MTOT + vcol0 + o);
    }
    int mreg = mask[mbase + lane];

    const int QTR = SEQ / NKV;   // 512 -> 8 tiles
    for (int t = 0; t < QTR; t += 64) {
        __syncthreads();   // all waves done reading LDS from previous tile

        // stage tile t (coalesced half8 stores)
        #pragma unroll
        for (int i = 0; i < 4; ++i) {
            int c = tid + 128 * i, j = c >> 3, o = (c & 7) * 8;
            *(half8*)&Ks[j * 72 + o] = pfK[i];
            *(half8*)&Vs[j * 72 + o] = pfV[i];
        }
        int mcur = mreg;

        // prefetch next tile into regs (wraps within quarter; discarded last)
        {
            int t1 = (t + 64) & (QTR - 1);
            #pragma unroll
            for (int i = 0; i < 4; ++i) {
                int c = tid + 128 * i, j = c >> 3, o = (c & 7) * 8;
                pfK[i] = *(const half8*)(K  + kbase + (size_t)(kv0 + t1 + j) * HDIM + o);
                pfV[i] = *(const half8*)(Vt + (size_t)j * MTOT + vcol0 + t1 + o);
            }
            mreg = mask[mbase + t1 + lane];
        }

        __syncthreads();   // staged tile visible

        // mask bits: kv of reg r (tile half tt) = tt*32 + (r&3)+8*(r>>2)+4*h5
        unsigned long long bits = __ballot(mcur != 0);
        unsigned long long shb  = bits >> (4 * h5);
        unsigned w0 = (unsigned)shb, w1 = (unsigned)(shb >> 32);

        // ---- S-tiles (swapped): D[m=kv][n=q] ----
        float16v sa = {0.f}, sb = {0.f};
        #pragma unroll
        for (int i = 0; i < 4; ++i) {
            half8 ka0 = *(const half8*)&Ks[(r31)      * 72 + i * 16 + h5 * 8];
            half8 ka1 = *(const half8*)&Ks[(32 + r31) * 72 + i * 16 + h5 * 8];
            sa = __builtin_amdgcn_mfma_f32_32x32x16_f16(ka0, qb[i], sa, 0, 0, 0);
            sb = __builtin_amdgcn_mfma_f32_32x32x16_f16(ka1, qb[i], sb, 0, 0, 0);
        }

        // ---- softmax (fixed shift), pack to PV A-frags in registers ----
        half4 pa0[4], pa1[4];         // [g][j]: kv = tt*32 + g*8 + 4*h5 + j
        #pragma unroll
        for (int g = 0; g < 4; ++g) {
            #pragma unroll
            for (int j2 = 0; j2 < 4; ++j2) {
                const int r  = 4 * g + j2;
                const int pc = (r & 3) + 8 * (r >> 2);
                float t0 = fmaf(sa[r], 0.125f, -6.0f);
                if (!((w0 >> pc) & 1)) t0 = -1e30f;
                f16 p0 = (f16)__expf(t0);
                pa0[g][j2] = p0;
                float t1f = fmaf(sb[r], 0.125f, -6.0f);
                if (!((w1 >> pc) & 1)) t1f = -1e30f;
                f16 p1 = (f16)__expf(t1f);
                pa1[g][j2] = p1;
                la[j2] += (float)p0 + (float)p1;   // l from the rounded P
            }
        }

        // ---- PV: O += P V, A-frags direct from registers, V b64 reads ----
        #pragma unroll
        for (int g = 0; g < 4; ++g) {
            const int c0 = g * 8 + h5 * 4;       // kv-tile 0 cols
            const int c1 = 32 + c0;              // kv-tile 1 cols
            half4 vA0 = *(const half4*)&Vs[(r31)      * 72 + c0];
            half4 vA1 = *(const half4*)&Vs[(r31)      * 72 + c1];
            half4 vB0 = *(const half4*)&Vs[(32 + r31) * 72 + c0];
            half4 vB1 = *(const half4*)&Vs[(32 + r31) * 72 + c1];
            O0 = __builtin_amdgcn_mfma_f32_32x32x8f16(pa0[g], vA0, O0, 0, 0, 0);
            O0 = __builtin_amdgcn_mfma_f32_32x32x8f16(pa1[g], vA1, O0, 0, 0, 0);
            O1 = __builtin_amdgcn_mfma_f32_32x32x8f16(pa0[g], vB0, O1, 0, 0, 0);
            O1 = __builtin_amdgcn_mfma_f32_32x32x8f16(pa1[g], vB1, O1, 0, 0, 0);
        }
    }

    // ---- epilogue: partial l and partial (unnormalized) O ----
    float lsum = (la[0] + la[1]) + (la[2] + la[3]);   // this lane's kv subset
    lsum += __shfl_xor(lsum, 32, 64);                  // + partner half's subset
    if (lane < 32)
        Lpart[(size_t)kh * MTOT + b * SEQ + q0 + lane] = lsum;

    float* Ob = (kh == 0) ? Oout : (Opart + (size_t)(kh - 1) * ((size_t)MTOT * HDIM));
    #pragma unroll
    for (int r = 0; r < 16; ++r) {
        int q = (r & 3) + 8 * (r >> 2) + 4 * h5;
        size_t row = (size_t)(b * SEQ + q0 + q) * HDIM;
        Ob[row + r31]      = O0[r];
        Ob[row + 32 + r31] = O1[r];
    }
}

// ---------------------------------------------------------------------------
// Kernel 3: combine split-KV partials: out = (out + Σ Op[i]) / Σ l
// ---------------------------------------------------------------------------
__global__ __launch_bounds__(256)
void combine_kernel(const float* __restrict__ Op, const float* __restrict__ Lp,
                    float* __restrict__ out)
{
    const size_t NEF = (size_t)MTOT * HDIM;
    int e = (blockIdx.x * 256 + threadIdx.x) * 8;
    int m = e >> 6;   // row (8 floats stay within one 64-wide row)
    float l = Lp[m] + Lp[MTOT + m] + Lp[2 * MTOT + m] + Lp[3 * MTOT + m];
    float inv = 1.0f / l;
    float4 r0 = *(const float4*)(out + e);
    float4 r1 = *(const float4*)(out + e + 4);
    #pragma unroll
    for (int i = 0; i < 3; ++i) {
        float4 b0 = *(const float4*)(Op + i * NEF + e);
        float4 b1 = *(const float4*)(Op + i * NEF + e + 4);
        r0.x += b0.x; r0.y += b0.y; r0.z += b0.z; r0.w += b0.w;
        r1.x += b1.x; r1.y += b1.y; r1.z += b1.z; r1.w += b1.w;
    }
    r0.x *= inv; r0.y *= inv; r0.z *= inv; r0.w *= inv;
    r1.x *= inv; r1.y *= inv; r1.z *= inv; r1.w *= inv;
    *(float4*)(out + e)     = r0;
    *(float4*)(out + e + 4) = r1;
}

// ---------------------------------------------------------------------------
extern "C" void kernel_launch(void* const* d_in, const int* in_sizes, int n_in,
                              void* d_out, int out_size, void* d_ws, size_t ws_size,
                              hipStream_t stream) {
    const float* x    = (const float*)d_in[0];
    const int*   mask = (const int*)  d_in[1];
    const float* Wq   = (const float*)d_in[2];
    const float* bq   = (const float*)d_in[3];
    const float* Wk   = (const float*)d_in[4];
    const float* bk   = (const float*)d_in[5];
    const float* Wv   = (const float*)d_in[6];
    const float* bv   = (const float*)d_in[7];
    float* out = (float*)d_out;

    // workspace: Qf,Kf,Vt (fp16, 4MB each) + Wt (384KB) + Opart (3x8MB fp32)
    //            + Lpart (4x128KB fp32) ~= 37MB  (kh=0 partial lives in out)
    f16* Qf = (f16*)d_ws;
    f16* Kf = Qf + (size_t)NE;
    f16* Vt = Kf + (size_t)NE;
    f16* Wt = Vt + (size_t)NE;
    float* Opart = (float*)(Wt + 192 * EMBED);
    float* Lpart = Opart + 3 * (size_t)MTOT * HDIM;

    wprep_kernel<<<dim3(768), dim3(256), 0, stream>>>(Wq, Wk, Wv, Wt);

    qkv_mfma_kernel<<<dim3(MTOT / 64), dim3(256), 0, stream>>>(
        x, Wt, bq, bk, bv, Qf, Kf, Vt);

    attn_mfma_kernel<<<dim3(SEQ / 64, BATCH, NKV), dim3(128), 0, stream>>>(
        Qf, Kf, Vt, mask, out, Opart, Lpart);

    combine_kernel<<<dim3((MTOT * HDIM) / (256 * 8)), dim3(256), 0, stream>>>(
        Opart, Lpart, out);
}

// Round 9
// 262.780 us; speedup vs baseline: 1.1944x; 1.0987x over previous
//
#include <hip/hip_runtime.h>
#include <math.h>

#define EMBED 1024
#define HDIM  64
#define BATCH 16
#define SEQ   2048
#define MTOT  (BATCH*SEQ)   // 32768
#define NE    (MTOT*HDIM)   // elements per Q/K/V array
#define NKV   4             // split-KV ways

typedef _Float16 f16;
typedef __attribute__((ext_vector_type(8))) _Float16 half8;   // 4 VGPR MFMA frag
typedef __attribute__((ext_vector_type(4))) _Float16 half4;   // 2 VGPR (mfma8 A/B)
typedef __attribute__((ext_vector_type(4))) float  float4v;   // 16x16 C/D frag
typedef __attribute__((ext_vector_type(16))) float float16v;  // 32x32 C/D frag

// ---------------------------------------------------------------------------
// Kernel 0: W -> fp16, transposed+concatenated: Wt[192][1024] (tiny)
// ---------------------------------------------------------------------------
__global__ void wprep_kernel(const float* __restrict__ Wq, const float* __restrict__ Wk,
                             const float* __restrict__ Wv, f16* __restrict__ Wt)
{
    int e = blockIdx.x * 256 + threadIdx.x;     // e = gn*1024 + k
    if (e >= 192 * EMBED) return;
    int gn = e >> 10, k = e & 1023;
    int mat = gn >> 6, n = gn & 63;
    const float* W = (mat == 0) ? Wq : ((mat == 1) ? Wk : Wv);
    Wt[e] = (f16)W[k * HDIM + n];
}

// ---------------------------------------------------------------------------
// Kernel 1: fused QKV projection, fp16 MFMA (unchanged).
// ---------------------------------------------------------------------------
__global__ __launch_bounds__(256)
void qkv_mfma_kernel(const float* __restrict__ X, const f16* __restrict__ Wt,
                     const float* __restrict__ bq, const float* __restrict__ bk, const float* __restrict__ bv,
                     f16* __restrict__ Q, f16* __restrict__ K, f16* __restrict__ Vt)
{
    __shared__ f16 Xs[64 * 72];    // [m][k] pad 64->72 halves
    __shared__ f16 Csv[64 * 72];   // V epilogue transpose [d][m]

    const int tid  = threadIdx.x;
    const int wave = tid >> 6;
    const int lane = tid & 63;
    const int quad = lane >> 4;
    const int c16  = lane & 15;
    const int m0   = blockIdx.x * 64;
    const int gnb  = wave * 3;

    float4v acc[4][3];
    #pragma unroll
    for (int mt = 0; mt < 4; ++mt)
        #pragma unroll
        for (int nt = 0; nt < 3; ++nt)
            acc[mt][nt] = (float4v){0.f, 0.f, 0.f, 0.f};

    float4 pf[4];
    #pragma unroll
    for (int i = 0; i < 4; ++i) {
        int c = tid + 256 * i, m = c >> 4, ko = (c & 15) * 4;
        pf[i] = *(const float4*)(X + (size_t)(m0 + m) * EMBED + ko);
    }

    for (int k0 = 0; k0 < EMBED; k0 += 64) {
        half8 bh[2][3];
        #pragma unroll
        for (int ks = 0; ks < 2; ++ks)
            #pragma unroll
            for (int nt = 0; nt < 3; ++nt)
                bh[ks][nt] = *(const half8*)(Wt + (size_t)((gnb + nt) * 16 + c16) * EMBED
                                             + k0 + ks * 32 + quad * 8);

        __syncthreads();
        #pragma unroll
        for (int i = 0; i < 4; ++i) {
            int c = tid + 256 * i, m = c >> 4, ko = (c & 15) * 4;
            *(half4*)&Xs[m * 72 + ko] =
                (half4){ (f16)pf[i].x, (f16)pf[i].y, (f16)pf[i].z, (f16)pf[i].w };
        }
        __syncthreads();

        {
            int k1 = (k0 + 64) & (EMBED - 1);
            #pragma unroll
            for (int i = 0; i < 4; ++i) {
                int c = tid + 256 * i, m = c >> 4, ko = (c & 15) * 4;
                pf[i] = *(const float4*)(X + (size_t)(m0 + m) * EMBED + k1 + ko);
            }
        }

        #pragma unroll
        for (int ks = 0; ks < 2; ++ks) {
            half8 a[4];
            #pragma unroll
            for (int mt = 0; mt < 4; ++mt)
                a[mt] = *(const half8*)&Xs[(mt * 16 + c16) * 72 + ks * 32 + quad * 8];
            #pragma unroll
            for (int mt = 0; mt < 4; ++mt)
                #pragma unroll
                for (int nt = 0; nt < 3; ++nt)
                    acc[mt][nt] = __builtin_amdgcn_mfma_f32_16x16x32_f16(a[mt], bh[ks][nt], acc[mt][nt], 0, 0, 0);
        }
    }

    float bb[3];
    #pragma unroll
    for (int nt = 0; nt < 3; ++nt) {
        int gn = (gnb + nt) * 16 + c16, mat = gn >> 6, cn = gn & 63;
        bb[nt] = ((mat == 0) ? bq : ((mat == 1) ? bk : bv))[cn];
    }

    #pragma unroll
    for (int mt = 0; mt < 4; ++mt)
        #pragma unroll
        for (int nt = 0; nt < 3; ++nt) {
            int gn = (gnb + nt) * 16 + c16, mat = gn >> 6, cn = gn & 63;
            if (mat < 2) {
                f16* O = mat ? K : Q;
                #pragma unroll
                for (int r = 0; r < 4; ++r)
                    O[(size_t)(m0 + mt * 16 + quad * 4 + r) * HDIM + cn] =
                        (f16)(acc[mt][nt][r] + bb[nt]);
            }
        }

    __syncthreads();
    #pragma unroll
    for (int mt = 0; mt < 4; ++mt)
        #pragma unroll
        for (int nt = 0; nt < 3; ++nt) {
            int gn = (gnb + nt) * 16 + c16, mat = gn >> 6, cn = gn & 63;
            if (mat == 2) {
                #pragma unroll
                for (int r = 0; r < 4; ++r)
                    Csv[cn * 72 + mt * 16 + quad * 4 + r] = (f16)(acc[mt][nt][r] + bb[nt]);
            }
        }
    __syncthreads();
    {
        int d = tid >> 2, ms = (tid & 3) * 16;
        #pragma unroll
        for (int j = 0; j < 2; ++j)
            *(half8*)(Vt + (size_t)d * MTOT + m0 + ms + 8 * j) =
                *(const half8*)&Csv[d * 72 + ms + 8 * j];
    }
}

// ---------------------------------------------------------------------------
// Kernel 2: flash attention, register-resident P + LDS-staged K/V.
//   r8 architecture (single-buffer LDS 18.4KB, split-KV z=4, 2048 blocks,
//   8 blocks/CU by LDS) with the VGPR cap FIXED: __launch_bounds__(128, 2)
//   (r8's (128,4) forced VGPR=64 -> ~150-reg working set spilled to scratch:
//   164MB FETCH, VALUBusy 1%). Natural ~110 VGPR -> 4 waves/SIMD by VGPR,
//   8 blocks/CU by LDS = 16 waves/CU, zero spill.
//   Swapped QK^T: S = mfma_32x32x16(A=K, B=Q); lane holds
//   S[kv=(r&3)+8*(r>>2)+4*h5][q=r31]; exp+f16-pack in registers IS the
//   A-frag of mfma_32x32x8f16 for PV. l = register sum + shfl_xor(32).
//   Mask via one __ballot per tile. Fixed-shift softmax (linear -> split-KV
//   exact). kh=0 partial O -> out; kh=1..3 -> workspace slabs.
// ---------------------------------------------------------------------------
__global__ __launch_bounds__(128, 2)
void attn_mfma_kernel(const f16* __restrict__ Q, const f16* __restrict__ K,
                      const f16* __restrict__ Vt, const int* __restrict__ mask,
                      float* __restrict__ Oout, float* __restrict__ Opart,
                      float* __restrict__ Lpart)
{
    __shared__ f16 Ks[64 * 72];   // [kv][d] pad 64->72 (single buffer)
    __shared__ f16 Vs[64 * 72];   // [d][kv]

    const int tid  = threadIdx.x;
    const int wave = tid >> 6;
    const int lane = tid & 63;
    const int r31  = lane & 31;
    const int h5   = lane >> 5;
    const int b    = blockIdx.y;
    const int kh   = blockIdx.z;
    const int q0   = blockIdx.x * 64 + wave * 32;   // 32 q-rows per wave
    const int kv0  = kh * (SEQ / NKV);              // this block's kv quarter

    // Q B-frags: B[n=q=r31][k=d = i*16 + h5*8 + j], loaded once
    half8 qb[4];
    {
        const size_t qrow = (size_t)(b * SEQ + q0 + r31) * HDIM;
        #pragma unroll
        for (int i = 0; i < 4; ++i)
            qb[i] = *(const half8*)(Q + qrow + i * 16 + h5 * 8);
    }

    float16v O0 = {0.f}, O1 = {0.f};   // O[q][d cols r31 / 32+r31]
    float la[4] = {0.f, 0.f, 0.f, 0.f};

    const size_t kbase = (size_t)b * SEQ * HDIM;   // K: [SEQ][64] per batch
    const int vcol0 = b * SEQ + kv0;               // Vt: [64][MTOT]
    const int mbase = b * SEQ + kv0;

    // register prefetch of tile 0 (K,V: 8KB each; 128 thr -> 4 half8 each)
    half8 pfK[4], pfV[4];
    #pragma unroll
    for (int i = 0; i < 4; ++i) {
        int c = tid + 128 * i, j = c >> 3, o = (c & 7) * 8;
        pfK[i] = *(const half8*)(K  + kbase + (size_t)(kv0 + j) * HDIM + o);
        pfV[i] = *(const half8*)(Vt + (size_t)j * MTOT + vcol0 + o);
    }
    int mreg = mask[mbase + lane];

    const int QTR = SEQ / NKV;   // 512 -> 8 tiles
    for (int t = 0; t < QTR; t += 64) {
        __syncthreads();   // all waves done reading LDS from previous tile

        // stage tile t (coalesced half8 stores)
        #pragma unroll
        for (int i = 0; i < 4; ++i) {
            int c = tid + 128 * i, j = c >> 3, o = (c & 7) * 8;
            *(half8*)&Ks[j * 72 + o] = pfK[i];
            *(half8*)&Vs[j * 72 + o] = pfV[i];
        }
        int mcur = mreg;

        // prefetch next tile into regs (wraps within quarter; discarded last)
        {
            int t1 = (t + 64) & (QTR - 1);
            #pragma unroll
            for (int i = 0; i < 4; ++i) {
                int c = tid + 128 * i, j = c >> 3, o = (c & 7) * 8;
                pfK[i] = *(const half8*)(K  + kbase + (size_t)(kv0 + t1 + j) * HDIM + o);
                pfV[i] = *(const half8*)(Vt + (size_t)j * MTOT + vcol0 + t1 + o);
            }
            mreg = mask[mbase + t1 + lane];
        }

        __syncthreads();   // staged tile visible

        // mask bits: kv of reg r (tile half tt) = tt*32 + (r&3)+8*(r>>2)+4*h5
        unsigned long long bits = __ballot(mcur != 0);
        unsigned long long shb  = bits >> (4 * h5);
        unsigned w0 = (unsigned)shb, w1 = (unsigned)(shb >> 32);

        // ---- S-tiles (swapped): D[m=kv][n=q] ----
        float16v sa = {0.f}, sb = {0.f};
        #pragma unroll
        for (int i = 0; i < 4; ++i) {
            half8 ka0 = *(const half8*)&Ks[(r31)      * 72 + i * 16 + h5 * 8];
            half8 ka1 = *(const half8*)&Ks[(32 + r31) * 72 + i * 16 + h5 * 8];
            sa = __builtin_amdgcn_mfma_f32_32x32x16_f16(ka0, qb[i], sa, 0, 0, 0);
            sb = __builtin_amdgcn_mfma_f32_32x32x16_f16(ka1, qb[i], sb, 0, 0, 0);
        }

        // ---- softmax (fixed shift), pack to PV A-frags in registers ----
        half4 pa0[4], pa1[4];         // [g][j]: kv = tt*32 + g*8 + 4*h5 + j
        #pragma unroll
        for (int g = 0; g < 4; ++g) {
            #pragma unroll
            for (int j2 = 0; j2 < 4; ++j2) {
                const int r  = 4 * g + j2;
                const int pc = (r & 3) + 8 * (r >> 2);
                float t0 = fmaf(sa[r], 0.125f, -6.0f);
                if (!((w0 >> pc) & 1)) t0 = -1e30f;
                f16 p0 = (f16)__expf(t0);
                pa0[g][j2] = p0;
                float t1f = fmaf(sb[r], 0.125f, -6.0f);
                if (!((w1 >> pc) & 1)) t1f = -1e30f;
                f16 p1 = (f16)__expf(t1f);
                pa1[g][j2] = p1;
                la[j2] += (float)p0 + (float)p1;   // l from the rounded P
            }
        }

        // ---- PV: O += P V, A-frags direct from registers, V b64 reads ----
        #pragma unroll
        for (int g = 0; g < 4; ++g) {
            const int c0 = g * 8 + h5 * 4;       // kv-tile 0 cols
            const int c1 = 32 + c0;              // kv-tile 1 cols
            half4 vA0 = *(const half4*)&Vs[(r31)      * 72 + c0];
            half4 vA1 = *(const half4*)&Vs[(r31)      * 72 + c1];
            half4 vB0 = *(const half4*)&Vs[(32 + r31) * 72 + c0];
            half4 vB1 = *(const half4*)&Vs[(32 + r31) * 72 + c1];
            O0 = __builtin_amdgcn_mfma_f32_32x32x8f16(pa0[g], vA0, O0, 0, 0, 0);
            O0 = __builtin_amdgcn_mfma_f32_32x32x8f16(pa1[g], vA1, O0, 0, 0, 0);
            O1 = __builtin_amdgcn_mfma_f32_32x32x8f16(pa0[g], vB0, O1, 0, 0, 0);
            O1 = __builtin_amdgcn_mfma_f32_32x32x8f16(pa1[g], vB1, O1, 0, 0, 0);
        }
    }

    // ---- epilogue: partial l and partial (unnormalized) O ----
    float lsum = (la[0] + la[1]) + (la[2] + la[3]);   // this lane's kv subset
    lsum += __shfl_xor(lsum, 32, 64);                  // + partner half's subset
    if (lane < 32)
        Lpart[(size_t)kh * MTOT + b * SEQ + q0 + lane] = lsum;

    float* Ob = (kh == 0) ? Oout : (Opart + (size_t)(kh - 1) * ((size_t)MTOT * HDIM));
    #pragma unroll
    for (int r = 0; r < 16; ++r) {
        int q = (r & 3) + 8 * (r >> 2) + 4 * h5;
        size_t row = (size_t)(b * SEQ + q0 + q) * HDIM;
        Ob[row + r31]      = O0[r];
        Ob[row + 32 + r31] = O1[r];
    }
}

// ---------------------------------------------------------------------------
// Kernel 3: combine split-KV partials: out = (out + Σ Op[i]) / Σ l
// ---------------------------------------------------------------------------
__global__ __launch_bounds__(256)
void combine_kernel(const float* __restrict__ Op, const float* __restrict__ Lp,
                    float* __restrict__ out)
{
    const size_t NEF = (size_t)MTOT * HDIM;
    int e = (blockIdx.x * 256 + threadIdx.x) * 8;
    int m = e >> 6;   // row (8 floats stay within one 64-wide row)
    float l = Lp[m] + Lp[MTOT + m] + Lp[2 * MTOT + m] + Lp[3 * MTOT + m];
    float inv = 1.0f / l;
    float4 r0 = *(const float4*)(out + e);
    float4 r1 = *(const float4*)(out + e + 4);
    #pragma unroll
    for (int i = 0; i < 3; ++i) {
        float4 b0 = *(const float4*)(Op + i * NEF + e);
        float4 b1 = *(const float4*)(Op + i * NEF + e + 4);
        r0.x += b0.x; r0.y += b0.y; r0.z += b0.z; r0.w += b0.w;
        r1.x += b1.x; r1.y += b1.y; r1.z += b1.z; r1.w += b1.w;
    }
    r0.x *= inv; r0.y *= inv; r0.z *= inv; r0.w *= inv;
    r1.x *= inv; r1.y *= inv; r1.z *= inv; r1.w *= inv;
    *(float4*)(out + e)     = r0;
    *(float4*)(out + e + 4) = r1;
}

// ---------------------------------------------------------------------------
extern "C" void kernel_launch(void* const* d_in, const int* in_sizes, int n_in,
                              void* d_out, int out_size, void* d_ws, size_t ws_size,
                              hipStream_t stream) {
    const float* x    = (const float*)d_in[0];
    const int*   mask = (const int*)  d_in[1];
    const float* Wq   = (const float*)d_in[2];
    const float* bq   = (const float*)d_in[3];
    const float* Wk   = (const float*)d_in[4];
    const float* bk   = (const float*)d_in[5];
    const float* Wv   = (const float*)d_in[6];
    const float* bv   = (const float*)d_in[7];
    float* out = (float*)d_out;

    // workspace: Qf,Kf,Vt (fp16, 4MB each) + Wt (384KB) + Opart (3x8MB fp32)
    //            + Lpart (4x128KB fp32) ~= 37MB  (kh=0 partial lives in out)
    f16* Qf = (f16*)d_ws;
    f16* Kf = Qf + (size_t)NE;
    f16* Vt = Kf + (size_t)NE;
    f16* Wt = Vt + (size_t)NE;
    float* Opart = (float*)(Wt + 192 * EMBED);
    float* Lpart = Opart + 3 * (size_t)MTOT * HDIM;

    wprep_kernel<<<dim3(768), dim3(256), 0, stream>>>(Wq, Wk, Wv, Wt);

    qkv_mfma_kernel<<<dim3(MTOT / 64), dim3(256), 0, stream>>>(
        x, Wt, bq, bk, bv, Qf, Kf, Vt);

    attn_mfma_kernel<<<dim3(SEQ / 64, BATCH, NKV), dim3(128), 0, stream>>>(
        Qf, Kf, Vt, mask, out, Opart, Lpart);

    combine_kernel<<<dim3((MTOT * HDIM) / (256 * 8)), dim3(256), 0, stream>>>(
        Opart, Lpart, out);
}